// Round 1
// 117.493 us; speedup vs baseline: 1.0590x; 1.0590x over previous
//
#include <hip/hip_runtime.h>
#include <stdint.h>

#define B 128
#define F 8192
#define H 8192
#define S 4
#define K 32
#define L 3
#define C 100

// ---------------------------------------------------------------------------
// Planar-PAIR activation layout: PP[wp][h] = uint2{ word(2wp), word(2wp+1) },
// wp in {0,1}; word w covers batches w*32..w*32+31, bit = b & 31.
// As u32 array: index (wp*H + h)*2 + comp.
// ---------------------------------------------------------------------------

// ---------------------------------------------------------------------------
// Pack x (B,F) float {0,1} -> xPP pair layout. Block = 128 threads (thread=b),
// 32 f per block. Wave wv covers b in [64wv, 64wv+64) -> word pair wv.
// Also zeroes d_out (fused).
// ---------------------------------------------------------------------------
__global__ void pack_x_kernel(const float* __restrict__ x, uint2* __restrict__ xPP,
                              float* __restrict__ out) {
    const int zi = blockIdx.x * 128 + threadIdx.x;
    if (zi < B * C) out[zi] = 0.0f;

    const int b  = threadIdx.x;          // 0..127
    const int wv = threadIdx.x >> 6;     // word pair (0,1)
    const int f0 = blockIdx.x * 32;
    const float4* xr = (const float4*)(x + (size_t)b * F + f0);
    for (int j = 0; j < 8; ++j) {
        const float4 v = xr[j];
        const uint64_t m0 = __ballot(v.x > 0.5f);
        const uint64_t m1 = __ballot(v.y > 0.5f);
        const uint64_t m2 = __ballot(v.z > 0.5f);
        const uint64_t m3 = __ballot(v.w > 0.5f);
        if ((threadIdx.x & 63) == 0) {
            const int f = f0 + 4 * j;
            uint4* dst = (uint4*)(xPP + (size_t)wv * F + f);
            dst[0] = make_uint4((uint32_t)m0, (uint32_t)(m0 >> 32),
                                (uint32_t)m1, (uint32_t)(m1 >> 32));
            dst[1] = make_uint4((uint32_t)m2, (uint32_t)(m2 >> 32),
                                (uint32_t)m3, (uint32_t)(m3 >> 32));
        }
    }
}

__device__ __forceinline__ int load_threshold(const int* p) {
    int v = *p;
    if (v >= (1 << 23)) v = (int)__int_as_float(v);
    return v;
}

// carry-save add of one 0/1-mask word into a 5-deep bit-sliced counter
__device__ __forceinline__ void cs5(uint32_t* a, uint32_t v) {
#pragma unroll
    for (int i = 0; i < 5; ++i) { const uint32_t t = a[i]; a[i] = t ^ v; v = t & v; }
}

// sum own 5-bit sliced counter with lane^32 partner's -> 6-bit result in y
__device__ __forceinline__ void pair_sum5(const uint32_t* x, uint32_t* y) {
    uint32_t c = 0;
#pragma unroll
    for (int i = 0; i < 5; ++i) {
        const uint32_t p = (uint32_t)__shfl_xor((int)x[i], 32);
        const uint32_t s = x[i] ^ p;
        y[i] = s ^ c;
        c = (x[i] & p) | (s & c);
    }
    y[5] = c;
}

// fired = (2P >= A + thr), bit-sliced over 7 bits; A,P are 6-deep (<=32)
__device__ __forceinline__ uint32_t fired_cmp(const uint32_t* A, const uint32_t* P, int thr) {
    uint32_t Y[7];
    uint32_t c = 0;
#pragma unroll
    for (int i = 0; i < 7; ++i) {
        const uint32_t ai = (i < 6) ? A[i] : 0u;
        const uint32_t bm = ((thr >> i) & 1) ? 0xFFFFFFFFu : 0u;
        const uint32_t t  = ai ^ bm;
        Y[i] = t ^ c;
        c = (ai & bm) | (t & c);
    }
    uint32_t bw = 0;
#pragma unroll
    for (int i = 0; i < 7; ++i) {
        const uint32_t xx = (i >= 1) ? P[i - 1] : 0u;
        const uint32_t d  = xx ^ Y[i];
        bw = ((~xx) & Y[i]) | ((~d) & bw);
    }
    return ~bw;
}

// async global->LDS, 16 B per lane
#define GLDS16(gp, lp)                                                \
    __builtin_amdgcn_global_load_lds(                                 \
        (const __attribute__((address_space(1))) uint32_t*)(gp),      \
        (__attribute__((address_space(3))) uint32_t*)(lp), 16, 0, 0)

// ---------------------------------------------------------------------------
// Layer: block = 32 h-rows x ALL 4 words x ALL 4 segments. 512 threads,
// grid = H/32 = 256 = 1 block/CU (151 KiB LDS).
//  - tab[2][H] uint2: full prev activation in pair layout, staged contiguous
//    via global_load_lds dwordx4 (16 rounds, fire-and-forget).
//  - isg: packed (idx | signbit) staged ONCE per block (no w-redundancy).
//    Row stride 35 u32 (odd) -> scalar b32 reads are conflict-free (2-way).
//  - wave ww: s = ww&3, wp = ww>>2. lane: h5 = lane&31, kh = lane>>5
//    (K split 16/16 across lane^32). Gather uint2 -> carry-save counters for
//    BOTH words of the pair; pair-sum over kh via shfl_xor(32); bit-sliced
//    compare; OR across segments via LDS.
// ---------------------------------------------------------------------------
#define HG 32
#define ISTRIDE 35

__global__ __launch_bounds__(512, 2) void layer_kernel(
        const uint32_t* __restrict__ prevPP,   // [2][H] uint2, as u32*
        const int* __restrict__ idx,           // (S,H,K)
        const float* __restrict__ signs,       // (S,H,K)
        uint32_t* __restrict__ outPP,          // [2][H] uint2, as u32*
        const int* __restrict__ thrp) {
    __shared__ uint2    tab[2 * H];                  // 128 KiB
    __shared__ uint32_t isg[S * HG * ISTRIDE];       // 17.5 KiB
    __shared__ uint32_t fbuf[8 * HG * 2];            // 2 KiB

    const int tid = threadIdx.x;
    const int hg  = blockIdx.x;
    const int thr = load_threshold(thrp);

    // ---- stage tab: 128 KiB contiguous, async direct-to-LDS ----
    {
        uint32_t* lbase = (uint32_t*)&tab[0];
#pragma unroll
        for (int i = 0; i < 16; ++i) {
            const int o = (i * 512 + tid) * 4;      // u32 index, 16B/lane
            GLDS16(prevPP + o, lbase + o);
        }
    }
    // ---- stage isg once: thread t packs 8 entries (coalesced 32B reads) ----
    {
        const int s    = tid >> 7;                  // 0..3
        const int hrow = (tid & 127) >> 2;          // 0..31
        const int k0   = (tid & 3) * 8;             // 0,8,16,24
        const size_t gb = ((size_t)s * H + (size_t)hg * HG + hrow) * K + k0;
        const int4   ia = *(const int4*)(idx + gb);
        const int4   ic = *(const int4*)(idx + gb + 4);
        const float4 sa = *(const float4*)(signs + gb);
        const float4 sc = *(const float4*)(signs + gb + 4);
        uint32_t* dst = &isg[(s * HG + hrow) * ISTRIDE + k0];
        dst[0] = (uint32_t)ia.x | ((uint32_t)__float_as_int(sa.x) & 0x80000000u);
        dst[1] = (uint32_t)ia.y | ((uint32_t)__float_as_int(sa.y) & 0x80000000u);
        dst[2] = (uint32_t)ia.z | ((uint32_t)__float_as_int(sa.z) & 0x80000000u);
        dst[3] = (uint32_t)ia.w | ((uint32_t)__float_as_int(sa.w) & 0x80000000u);
        dst[4] = (uint32_t)ic.x | ((uint32_t)__float_as_int(sc.x) & 0x80000000u);
        dst[5] = (uint32_t)ic.y | ((uint32_t)__float_as_int(sc.y) & 0x80000000u);
        dst[6] = (uint32_t)ic.z | ((uint32_t)__float_as_int(sc.z) & 0x80000000u);
        dst[7] = (uint32_t)ic.w | ((uint32_t)__float_as_int(sc.w) & 0x80000000u);
    }
    __syncthreads();   // drains vmcnt (global_load_lds) + lgkmcnt (ds_writes)

    // ---- gather + bit-sliced accumulate (2 words per gather) ----
    const int lane = tid & 63;
    const int ww   = tid >> 6;        // 0..7
    const int s    = ww & 3;
    const int wp   = ww >> 2;
    const int kh   = lane >> 5;       // k half: 0 -> k0..15, 1 -> k16..31
    const int h5   = lane & 31;

    uint32_t A0[5] = {0,0,0,0,0}, P0[5] = {0,0,0,0,0};
    uint32_t A1[5] = {0,0,0,0,0}, P1[5] = {0,0,0,0,0};
    const uint32_t* row = &isg[(s * HG + h5) * ISTRIDE + kh * 16];
    const uint2*    tw  = &tab[wp * H];
#pragma unroll
    for (int c8 = 0; c8 < 2; ++c8) {
        uint32_t iv[8];
#pragma unroll
        for (int j = 0; j < 8; ++j) iv[j] = row[c8 * 8 + j];
        uint2 g[8];
#pragma unroll
        for (int j = 0; j < 8; ++j) g[j] = tw[iv[j] & 0xFFFFu];
#pragma unroll
        for (int j = 0; j < 8; ++j) {
            const uint32_t pm = ~(uint32_t)((int32_t)iv[j] >> 31);  // ~0 if +
            cs5(A0, g[j].x);
            cs5(P0, g[j].x & pm);
            cs5(A1, g[j].y);
            cs5(P1, g[j].y & pm);
        }
    }

    // ---- combine k halves (lane^32) -> 6-bit counters ----
    uint32_t A0f[6], P0f[6], A1f[6], P1f[6];
    pair_sum5(A0, A0f);
    pair_sum5(P0, P0f);
    pair_sum5(A1, A1f);
    pair_sum5(P1, P1f);

    const uint32_t f0 = fired_cmp(A0f, P0f, thr);   // word 2wp
    const uint32_t f1 = fired_cmp(A1f, P1f, thr);   // word 2wp+1

    if (kh == 0) {
        fbuf[(ww * HG + h5) * 2 + 0] = f0;
        fbuf[(ww * HG + h5) * 2 + 1] = f1;
    }
    __syncthreads();

    // ---- OR across 4 segments, write 128 u32 (coalesced) ----
    if (tid < 128) {
        const int wp2  = tid >> 6;
        const int comp = (tid >> 5) & 1;
        const int hh   = tid & 31;
        uint32_t v = 0;
#pragma unroll
        for (int s2 = 0; s2 < 4; ++s2)
            v |= fbuf[((wp2 * 4 + s2) * HG + hh) * 2 + comp];
        outPP[((size_t)wp2 * H + (size_t)hg * HG + hh) * 2 + comp] = v;
    }
}

// ---------------------------------------------------------------------------
// out[b][c] = sum_l sum_h act[l][b][h] * wout[l][h][c], act in {0,1}.
// Wave = one b; lanes = c. Pair layout read: u32 index
// ((l*2+wp)*H + h)*2 + comp, wp = (b>>5)>>1, comp = (b>>5)&1.
// ---------------------------------------------------------------------------
#define NHC 32
#define HCH (H / NHC)   // 256 h per chunk

__global__ void final_kernel(const uint32_t* __restrict__ actU,
                             const float* __restrict__ wout,
                             float* __restrict__ out) {
    const int lane = threadIdx.x & 63;
    const int wid  = threadIdx.x >> 6;          // 0..3
    const int hc   = blockIdx.x & (NHC - 1);
    const int bg   = blockIdx.x / NHC;          // 0..31
    const int b    = bg * 4 + wid;              // wave-uniform
    const int w32  = b >> 5;
    const int wp   = w32 >> 1;
    const int comp = w32 & 1;
    const int bit  = b & 31;

    float acc0 = 0.0f, acc1 = 0.0f;
    const int c1 = 64 + lane;
    const bool c1v = (c1 < C);

    for (int l = 0; l < L; ++l) {
        const uint32_t* aT = actU + ((size_t)(l * 2 + wp) * H) * 2 + comp;
        const float* wl = wout + (size_t)l * H * C;
        for (int r = 0; r < HCH / 64; ++r) {
            const int hbase = hc * HCH + r * 64;
            const uint32_t m = aT[(size_t)(hbase + lane) * 2];
            uint64_t hm = __ballot((m >> bit) & 1u);
            while (hm) {
                const int slot = __ffsll((unsigned long long)hm) - 1;
                hm &= hm - 1;
                const float* wr = wl + (size_t)(hbase + slot) * C;
                acc0 += wr[lane];
                if (c1v) acc1 += wr[c1];
            }
        }
    }
    atomicAdd(&out[b * C + lane], acc0);
    if (c1v) atomicAdd(&out[b * C + c1], acc1);
}

// ---------------------------------------------------------------------------
extern "C" void kernel_launch(void* const* d_in, const int* in_sizes, int n_in,
                              void* d_out, int out_size, void* d_ws, size_t ws_size,
                              hipStream_t stream) {
    const float* x      = (const float*)d_in[0];   // (B,F)
    const float* signs0 = (const float*)d_in[1];   // (S,H,K)
    const float* signsH = (const float*)d_in[2];   // (L-1,S,H,K)
    const float* wout   = (const float*)d_in[3];   // (L,H,C)
    const int*   idx0   = (const int*)d_in[4];     // (S,H,K)
    const int*   idxH   = (const int*)d_in[5];     // (L-1,S,H,K)
    const int*   thr    = (const int*)d_in[6];     // scalar
    float* out = (float*)d_out;                    // (B,C)

    // Workspace: xPP [2][F] uint2 (128 KiB), actPP [L][2][H] uint2 (384 KiB)
    uint32_t* xPP   = (uint32_t*)d_ws;
    uint32_t* actPP = xPP + (size_t)4 * F;

    pack_x_kernel<<<F / 32, 128, 0, stream>>>(x, (uint2*)xPP, out);

    layer_kernel<<<H / HG, 512, 0, stream>>>(xPP, idx0, signs0, actPP, thr);
    layer_kernel<<<H / HG, 512, 0, stream>>>(actPP, idxH, signsH,
                                             actPP + (size_t)4 * H, thr);
    layer_kernel<<<H / HG, 512, 0, stream>>>(actPP + (size_t)4 * H,
                                             idxH + (size_t)S * H * K,
                                             signsH + (size_t)S * H * K,
                                             actPP + (size_t)8 * H, thr);

    final_kernel<<<32 * NHC, 256, 0, stream>>>(actPP, wout, out);
}